// Round 15
// baseline (232.675 us; speedup 1.0000x reference)
//
#include <hip/hip_runtime.h>
#include <math.h>

// Problem constants (fixed-shape problem)
#define B_  16
#define D_  37
#define F_  4096
#define I_  64
#define EPS 1e-5f
// softmax scale 1/sqrt(64) folded with log2(e) into q at projection time,
// so S_mfma = att*log2e and softmax is a raw exp2. |att|<=8 (LN rows have
// norm exactly 8) -> exp2(S) <= 2^11.6: no max pass, bf16-safe unnormalized P.
#define QSCALE 0.18033688011112042f
#define NQS 4           // stats q-split (partial-Z planes)
#define NKS 2           // out k-split (f32 out + bf16 partial)

typedef unsigned short u16;
typedef __bf16 bf16x8 __attribute__((ext_vector_type(8)));
typedef __bf16 bf16x2v __attribute__((ext_vector_type(2)));
typedef float  f32x16 __attribute__((ext_vector_type(16)));
typedef float  f32x2v __attribute__((ext_vector_type(2)));
typedef unsigned int u32x4 __attribute__((ext_vector_type(4)));
typedef int i32x2 __attribute__((ext_vector_type(2)));

#define ZERO16 {0,0,0,0, 0,0,0,0, 0,0,0,0, 0,0,0,0}
#define MFMA32(a, b, c) __builtin_amdgcn_mfma_f32_32x32x16_bf16((a), (b), (c), 0, 0, 0)

#if __has_builtin(__builtin_amdgcn_exp2f)
#define EX2(x) __builtin_amdgcn_exp2f(x)
#else
#define EX2(x) exp2f(x)
#endif
#if __has_builtin(__builtin_amdgcn_rcpf)
#define RCP(x) __builtin_amdgcn_rcpf(x)
#else
#define RCP(x) (1.f / (x))
#endif

// fp32 -> bf16 RNE (scalar)
__device__ __forceinline__ u16 f2b(float f) {
  unsigned u = __builtin_bit_cast(unsigned, f);
  return (u16)((u + 0x7fffu + ((u >> 16) & 1u)) >> 16);
}
// bf16 bits -> fp32
__device__ __forceinline__ float b2f(u16 h) {
  return __builtin_bit_cast(float, (unsigned)h << 16);
}
// pack two fp32 -> bf16x2 (one v_cvt_pk_bf16_f32, RNE -- same rounding as f2b)
__device__ __forceinline__ unsigned pk2(float lo, float hi) {
  f32x2v f = {lo, hi};
  bf16x2v h = __builtin_convertvector(f, bf16x2v);
  return __builtin_bit_cast(unsigned, h);
}

// half-wave register swap (v_permlane32_swap_b32 on gfx950)
__device__ __forceinline__ void plswap(unsigned& a, unsigned& b) {
#if __has_builtin(__builtin_amdgcn_permlane32_swap)
  i32x2 r = __builtin_amdgcn_permlane32_swap((int)a, (int)b, false, false);
  a = (unsigned)r[0];
  b = (unsigned)r[1];
#else
  const int lh = (int)((threadIdx.x & 63) >> 5);
  unsigned pa = (unsigned)__shfl_xor((int)a, 32, 64);
  unsigned pb = (unsigned)__shfl_xor((int)b, 32, 64);
  unsigned na = lh ? pb : a;
  unsigned nb = lh ? b : pa;
  a = na;
  b = nb;
#endif
}

// From one S^T 32x32 C-block (rows=k, cols=q), build two PV A-fragments
// (m=q, contraction k): f0 = k 0..15, f1 = k 16..31 of this block.
// C-reg r holds k=(r&3)+8*(r>>2)+4*lh; A-frag VGPR j needs k=lh*8+2j(+1).
__device__ __forceinline__ void build_af(const f32x16& s, bf16x8& f0, bf16x8& f1) {
  float e[16];
#pragma unroll
  for (int r = 0; r < 16; ++r) e[r] = EX2(s[r]);
  unsigned a = pk2(e[0], e[1]),   bq = pk2(e[2], e[3]);
  unsigned c = pk2(e[4], e[5]),   d  = pk2(e[6], e[7]);
  plswap(a, c);
  plswap(bq, d);
  u32x4 v0 = {a, bq, c, d};
  f0 = __builtin_bit_cast(bf16x8, v0);
  unsigned ee = pk2(e[8], e[9]),  ff = pk2(e[10], e[11]);
  unsigned g  = pk2(e[12], e[13]), h = pk2(e[14], e[15]);
  plswap(ee, g);
  plswap(ff, h);
  u32x4 v1 = {ee, ff, g, h};
  f1 = __builtin_bit_cast(bf16x8, v1);
}

// ---------------------------------------------------------------------------
// Swizzled LDS tiles: logical [rows][64] bf16, elem (r,c) at
//   r*64 + ((c>>3 ^ (r&7))<<3) + (c&7)
// -> 16B-aligned b128 reads AND conflict-free banks without padding.
// ---------------------------------------------------------------------------
__device__ __forceinline__ bf16x8 ldfrag(const u16* base, int row, int kb) {
  return *(const bf16x8*)(base + (row << 6) + ((kb ^ (row & 7)) << 3));
}
// hoisted-staging helpers: LDS offset and global offset for chunk index c
__device__ __forceinline__ int soff_l(int c) {
  const int r = c >> 3, cb = c & 7;
  return (r << 6) + ((cb ^ (r & 7)) << 3);
}
__device__ __forceinline__ int soff_g(int c, int spitch) {
  return (c >> 3) * spitch + ((c & 7) << 3);
}

// XCD-chunked bijective block swizzles: cluster blocks that stream the same
// K/V (or Q) panels onto one XCD's L2.
__device__ __forceinline__ int swz512(int wg) {
  return (wg & 7) * 64 + (wg >> 3);
}
__device__ __forceinline__ int swz1024(int wg) {
  return (wg & 7) * 128 + (wg >> 3);
}

// ---------------------------------------------------------------------------
// Kernel 1: qkv projection + LayerNorm -> bf16 (r10-verified). W columns in
// 120 VGPRs, x staged transposed xs[64][44]; 10 broadcast ds_read_b128 +
// 120 FMA per output row. v written transposed vt[b][i][f] via vtile.
// ---------------------------------------------------------------------------
__global__ __launch_bounds__(256) void qkv_ln_k(
    const float* __restrict__ x,
    const float* __restrict__ Wq, const float* __restrict__ Wk,
    const float* __restrict__ Wv,
    u16* __restrict__ qn, u16* __restrict__ kn, u16* __restrict__ vt) {
  __shared__ __align__(16) float xs[64 * 44];   // [fl][d], pad 44
  __shared__ __align__(16) u16 vtile[64 * 72];

  const int t = threadIdx.x;
  const int b = blockIdx.y;
  const int f0 = blockIdx.x * 64;
  const int lane = t & 63, w = t >> 6;

  // W columns (i = lane) into registers; coalesced, L1/L2-shared.
  float wq[40], wk[40], wv[40];
#pragma unroll
  for (int d = 0; d < D_; ++d) {
    wq[d] = Wq[d * I_ + lane];
    wk[d] = Wk[d * I_ + lane];
    wv[d] = Wv[d * I_ + lane];
  }
#pragma unroll
  for (int d = D_; d < 40; ++d) { wq[d] = 0.f; wk[d] = 0.f; wv[d] = 0.f; }

  // stage x transposed: xs[fl][d] = x[b][d][f0+fl] (global reads coalesced)
  const float* xb = x + (size_t)b * D_ * F_ + f0;
  for (int i = t; i < D_ * 64; i += 256) {
    const int d = i >> 6, fl = i & 63;
    xs[fl * 44 + d] = xb[(size_t)d * F_ + fl];
  }
  // zero the d-pad (37..39) so padded FMA adds exact 0
  if (t < 192) {
    const int fl = t / 3, dp = 37 + (t % 3);
    xs[fl * 44 + dp] = 0.f;
  }
  __syncthreads();

  for (int it = 0; it < 16; ++it) {
    const int fl = w * 16 + it;
    const float* xr = &xs[fl * 44];
    float hq = 0.f, hk = 0.f, hv = 0.f;
#pragma unroll
    for (int j = 0; j < 10; ++j) {
      const float4 xv = *(const float4*)(xr + j * 4);   // broadcast b128
      hq = fmaf(xv.x, wq[4*j+0], hq); hk = fmaf(xv.x, wk[4*j+0], hk); hv = fmaf(xv.x, wv[4*j+0], hv);
      hq = fmaf(xv.y, wq[4*j+1], hq); hk = fmaf(xv.y, wk[4*j+1], hk); hv = fmaf(xv.y, wv[4*j+1], hv);
      hq = fmaf(xv.z, wq[4*j+2], hq); hk = fmaf(xv.z, wk[4*j+2], hk); hv = fmaf(xv.z, wv[4*j+2], hv);
      hq = fmaf(xv.w, wq[4*j+3], hq); hk = fmaf(xv.w, wk[4*j+3], hk); hv = fmaf(xv.w, wv[4*j+3], hv);
    }
    auto lnorm = [&](float a) -> float {
      float s = a;
#pragma unroll
      for (int o = 32; o > 0; o >>= 1) s += __shfl_xor(s, o, 64);
      const float mu = s * (1.f / 64.f);
      const float d0 = a - mu;
      float v = d0 * d0;
#pragma unroll
      for (int o = 32; o > 0; o >>= 1) v += __shfl_xor(v, o, 64);
      return d0 * rsqrtf(v * (1.f / 64.f) + EPS);
    };
    const size_t fo = ((size_t)b * F_ + f0 + fl) * I_ + lane;
    qn[fo] = f2b(lnorm(hq) * QSCALE);
    kn[fo] = f2b(lnorm(hk));
    vtile[lane * 72 + fl] = f2b(lnorm(hv));
  }
  __syncthreads();
  for (int p = 0; p < 2; ++p) {
    const int c = p * 256 + t;
    const int r = c >> 3, off = (c & 7) * 8;
    const int4 v = *(const int4*)&vtile[r * 72 + off];
    *(int4*)(vt + ((size_t)b * I_ + r) * F_ + f0 + off) = v;
  }
}

// ---------------------------------------------------------------------------
// Kernel 2: partial column-softmax sums zp[qh][b][k] = sum_{q in quarter}
// exp2(S). r9/r13-verified INNER STRUCTURE (kf[2][4], 64-k waves, double-
// chunk phases, sub-granular T14, M;M;E intra-wave pipeline) -- r14's wide-K
// restructure was neutral, so phase count is not the limiter. What IS: grid
// 512 = exactly 2 blocks/CU (grid-capped occupancy, the r2 pattern). NQS=4
// -> grid 1024 (16 ktiles x 16 b x 4 q-quarters) + (256,3): true liveness
// ~138 regs < 170 cap (margin, unlike r1's 128-cap spill / r3's 180-need)
// -> 3 blocks/CU, 12 waves/CU. K-hoist is 8 direct loads so the halved
// per-block amortization costs ~2%.
// ---------------------------------------------------------------------------
__global__ __launch_bounds__(256, 3) void attn_stats_k(
    const u16* __restrict__ qn, const u16* __restrict__ kn,
    float* __restrict__ zp) {
  __shared__ __align__(16) u16 sm[16384];   // 32 KB: Q dbuf 2 x (2 x 4096)

  const int t = threadIdx.x, lane = t & 63, w = t >> 6;
  const int l31 = lane & 31, lh = lane >> 5;
  // XCD-chunked decode: 16 consecutive logical ids share (b,qh).
  const int lg = swz1024((int)blockIdx.x);
  const int k0 = (lg & 15) * 256, b = (lg >> 4) & 15, qh = lg >> 8;

  // hoist own 64-k B-fragments directly from global (one-time, 8 loads)
  const u16* kp = kn + ((size_t)b * F_ + k0 + w * 64 + l31) * I_ + lh * 8;
  bf16x8 kf[2][4];
#pragma unroll
  for (int kb2 = 0; kb2 < 2; ++kb2)
#pragma unroll
    for (int ic = 0; ic < 4; ++ic)
      kf[kb2][ic] = *(const bf16x8*)(kp + kb2 * 32 * I_ + ic * 16);

  // hoisted Q staging offsets (2 chunks16B per thread per 64-q sub-tile)
  int qoff_l[2], qoff_g[2];
#pragma unroll
  for (int p = 0; p < 2; ++p) {
    const int c = p * 256 + t;
    qoff_l[p] = soff_l(c);
    qoff_g[p] = soff_g(c, 64);
  }

  const u16* qsrc = qn + ((size_t)b * F_ + qh * (F_ / NQS)) * I_;
  // prologue: stage phase 0 (both subs) into buffer 0
#pragma unroll
  for (int s = 0; s < 2; ++s)
#pragma unroll
    for (int p = 0; p < 2; ++p)
      *(int4*)(sm + s * 4096 + qoff_l[p]) =
          *(const int4*)(qsrc + s * 64 * I_ + qoff_g[p]);
  qsrc += 128 * I_;

  float Zc[2][2] = {{0.f, 0.f}, {0.f, 0.f}};  // [qb][kb]

  // MFMA group (sub given by Qc, qb): 4 ldfrag + 8 MFMA into t0(kb0), t1(kb1)
  auto Mg = [&](const u16* Qc, int qb, f32x16& t0, f32x16& t1) {
    __builtin_amdgcn_s_setprio(1);
#pragma unroll
    for (int ic = 0; ic < 4; ++ic) {
      const bf16x8 qv = ldfrag(Qc + qb * 32 * 64, l31, ic * 2 + lh);
      t0 = MFMA32(qv, kf[0][ic], t0);
      t1 = MFMA32(qv, kf[1][ic], t1);
    }
    __builtin_amdgcn_s_setprio(0);
  };
  // exp2-accumulate group (VALU)
  auto Eg = [&](int qb, const f32x16& t0, const f32x16& t1) {
#pragma unroll
    for (int r = 0; r < 16; ++r) {
      Zc[qb][0] += EX2(t0[r]);
      Zc[qb][1] += EX2(t1[r]);
    }
  };

  const int NC = F_ / NQS / 128;            // 8 double-chunk phases

  for (int c = 0; c < NC; ++c) {
    const int cur = (c & 1) * 8192;
    const int nxt = cur ^ 8192;
    const bool pf = (c + 1 < NC);
    __syncthreads();                        // cur staged; nxt's readers done
    int4 qr0, qr1;
    if (pf) {                               // T14: sub0' loads under compute
      qr0 = *(const int4*)(qsrc + qoff_g[0]);
      qr1 = *(const int4*)(qsrc + qoff_g[1]);
    }

    // pipeline: M(g) ; M(g+1) ; E(g) ...  (E overlaps next group's MFMAs)
    f32x16 sA0 = ZERO16, sA1 = ZERO16;
    Mg(sm + cur, 0, sA0, sA1);              // g0 = (sub0, qb0)
    f32x16 sB0 = ZERO16, sB1 = ZERO16;
    Mg(sm + cur, 1, sB0, sB1);              // g1 = (sub0, qb1)
    Eg(0, sA0, sA1);                        // E(g0) || M(g1)

    if (pf) {                               // stage sub0' ; load sub1'
      *(int4*)(sm + nxt + qoff_l[0]) = qr0;
      *(int4*)(sm + nxt + qoff_l[1]) = qr1;
      qr0 = *(const int4*)(qsrc + 64 * I_ + qoff_g[0]);
      qr1 = *(const int4*)(qsrc + 64 * I_ + qoff_g[1]);
    }

    f32x16 sC0 = ZERO16, sC1 = ZERO16;
    Mg(sm + cur + 4096, 0, sC0, sC1);       // g2 = (sub1, qb0)
    Eg(1, sB0, sB1);                        // E(g1) || M(g2)
    f32x16 sD0 = ZERO16, sD1 = ZERO16;
    Mg(sm + cur + 4096, 1, sD0, sD1);       // g3 = (sub1, qb1)
    Eg(0, sC0, sC1);                        // E(g2) || M(g3)

    if (pf) {                               // stage sub1'
      *(int4*)(sm + nxt + 4096 + qoff_l[0]) = qr0;
      *(int4*)(sm + nxt + 4096 + qoff_l[1]) = qr1;
      qsrc += 128 * I_;
    }
    Eg(1, sD0, sD1);                        // E(g3)
  }

#pragma unroll
  for (int kb2 = 0; kb2 < 2; ++kb2) {
    float Zt = Zc[0][kb2] + Zc[1][kb2];
    Zt += __shfl_xor(Zt, 32, 64);
    if (lane < 32)
      zp[((size_t)qh * B_ + b) * F_ + k0 + w * 64 + kb2 * 32 + lane] = Zt;
  }
}

// ---------------------------------------------------------------------------
// Kernel 3: partial out over a k-half. r13-verified (best attn_out: 75.9us):
// 256-q tile, 64-q waves, double-chunk phases, sub-granular T14, direct Q
// hoist, intra-wave MFMA/VALU pipeline, fused V-scaling at stage-write time
// with pk2 (v_cvt_pk_bf16_f32). rz table sums NQS=4 zp planes.
// ks=0 -> f32 out; ks=1 -> bf16 partial (reduce_k folds).
// ---------------------------------------------------------------------------
__global__ __launch_bounds__(256, 2) void attn_out_k(
    const u16* __restrict__ qn, const u16* __restrict__ kn,
    const u16* __restrict__ vt, const float* __restrict__ zp,
    float* __restrict__ out, u16* __restrict__ pout) {
  __shared__ __align__(16) u16 sm[32768];   // 64 KB: K dbuf 2x8192, V at 16384+
  __shared__ __align__(16) float rzs[F_ / NKS];  // 8 KB: 1/Z for this k-half

  const int t = threadIdx.x, lane = t & 63, w = t >> 6;
  const int l31 = lane & 31, lh = lane >> 5;
  // XCD-chunked decode: 16 consecutive logical ids share (b,ks).
  const int lg = swz512((int)blockIdx.x);
  const int q0 = (lg & 15) * 256, b = (lg >> 4) & 15, ks = lg >> 8;

  // ---- rz table: rzs[k] = RCP(sum_qh zp[qh][b][k]) for this k-half ----
  {
    const float* zb = zp + (size_t)b * F_ + ks * (F_ / NKS);
    const size_t PL = (size_t)B_ * F_;
    const int k8 = t * 8;                   // 256 thr x 8 = 2048
    float4 s0 = *(const float4*)(zb + k8);
    float4 s1 = *(const float4*)(zb + k8 + 4);
#pragma unroll
    for (int qh = 1; qh < NQS; ++qh) {
      const float4 a0 = *(const float4*)(zb + qh * PL + k8);
      const float4 a1 = *(const float4*)(zb + qh * PL + k8 + 4);
      s0.x += a0.x; s0.y += a0.y; s0.z += a0.z; s0.w += a0.w;
      s1.x += a1.x; s1.y += a1.y; s1.z += a1.z; s1.w += a1.w;
    }
    float4 r0, r1;
    r0.x = RCP(s0.x); r0.y = RCP(s0.y); r0.z = RCP(s0.z); r0.w = RCP(s0.w);
    r1.x = RCP(s1.x); r1.y = RCP(s1.y); r1.z = RCP(s1.z); r1.w = RCP(s1.w);
    *(float4*)(rzs + k8)     = r0;
    *(float4*)(rzs + k8 + 4) = r1;
  }
  __syncthreads();                          // rzs visible to all

  // hoist own 64-q B-fragments directly from global (one-time, 8 loads)
  const u16* qp = qn + ((size_t)b * F_ + q0 + w * 64 + l31) * I_ + lh * 8;
  bf16x8 qf[2][4];
#pragma unroll
  for (int qb2 = 0; qb2 < 2; ++qb2)
#pragma unroll
    for (int ic = 0; ic < 4; ++ic)
      qf[qb2][ic] = *(const bf16x8*)(qp + qb2 * 32 * I_ + ic * 16);

  // hoisted staging offsets (2 K + 2 V chunks16B per thread per 64-k sub)
  int off_l[2], kg[2], vg[2];
#pragma unroll
  for (int p = 0; p < 2; ++p) {
    const int c = p * 256 + t;
    off_l[p] = soff_l(c);
    kg[p] = soff_g(c, 64);
    vg[p] = soff_g(c, F_);
  }
  const int kw = (t & 7) * 8;               // k-col base of this thread's 16B

  // scale a staged V 16B-chunk by rzs[kb..kb+7]; pk2 = v_cvt_pk_bf16_f32
  auto vscale16 = [&](int4 raw, int kb) -> int4 {
    u16 es[8];
    *(int4*)es = raw;
    const float4 r0 = *(const float4*)(rzs + kb);
    const float4 r1 = *(const float4*)(rzs + kb + 4);
    unsigned o01 = pk2(b2f(es[0]) * r0.x, b2f(es[1]) * r0.y);
    unsigned o23 = pk2(b2f(es[2]) * r0.z, b2f(es[3]) * r0.w);
    unsigned o45 = pk2(b2f(es[4]) * r1.x, b2f(es[5]) * r1.y);
    unsigned o67 = pk2(b2f(es[6]) * r1.z, b2f(es[7]) * r1.w);
    u32x4 o = {o01, o23, o45, o67};
    return __builtin_bit_cast(int4, o);
  };

  const u16* ksrc = kn + ((size_t)b * F_ + ks * (F_ / NKS)) * I_;
  const u16* vsrc = vt + (size_t)b * I_ * F_ + ks * (F_ / NKS);
  // prologue: stage phase 0 (both subs) into buffers 0 (V scaled)
#pragma unroll
  for (int s = 0; s < 2; ++s)
#pragma unroll
    for (int p = 0; p < 2; ++p) {
      *(int4*)(sm + s * 4096 + off_l[p]) =
          *(const int4*)(ksrc + s * 64 * I_ + kg[p]);
      *(int4*)(sm + 16384 + s * 4096 + off_l[p]) =
          vscale16(*(const int4*)(vsrc + s * 64 + vg[p]), s * 64 + kw);
    }
  ksrc += 128 * I_;
  vsrc += 128;

  f32x16 o00 = ZERO16, o01 = ZERO16, o10 = ZERO16, o11 = ZERO16; // [qb][ih]

  // S group: one kh-half of one sub (Kc pre-offset): 4 ldfrag + 8 MFMA
  auto Sg = [&](const u16* Kc, f32x16& t0, f32x16& t1) {
    __builtin_amdgcn_s_setprio(1);
#pragma unroll
    for (int ic = 0; ic < 4; ++ic) {
      const bf16x8 ak = ldfrag(Kc, l31, ic * 2 + lh);
      t0 = MFMA32(ak, qf[0][ic], t0);
      t1 = MFMA32(ak, qf[1][ic], t1);
    }
    __builtin_amdgcn_s_setprio(0);
  };
  // exp2+transpose (VALU) then PV for that kh-half (kb4 = 2kh, 2kh+1)
  auto EPg = [&](const u16* Vc, int kh, const f32x16& t0, const f32x16& t1) {
    bf16x8 a0, a1, b0, b1;
    build_af(t0, a0, a1);                   // qb0: kb4=2kh -> a0, 2kh+1 -> a1
    build_af(t1, b0, b1);                   // qb1
    __builtin_amdgcn_s_setprio(1);
    {
      const int kb4 = kh * 2;
      const bf16x8 bv0 = ldfrag(Vc, l31, kb4 * 2 + lh);
      const bf16x8 bv1 = ldfrag(Vc + 32 * 64, l31, kb4 * 2 + lh);
      o00 = MFMA32(a0, bv0, o00);
      o01 = MFMA32(a0, bv1, o01);
      o10 = MFMA32(b0, bv0, o10);
      o11 = MFMA32(b0, bv1, o11);
    }
    {
      const int kb4 = kh * 2 + 1;
      const bf16x8 bv0 = ldfrag(Vc, l31, kb4 * 2 + lh);
      const bf16x8 bv1 = ldfrag(Vc + 32 * 64, l31, kb4 * 2 + lh);
      o00 = MFMA32(a1, bv0, o00);
      o01 = MFMA32(a1, bv1, o01);
      o10 = MFMA32(b1, bv0, o10);
      o11 = MFMA32(b1, bv1, o11);
    }
    __builtin_amdgcn_s_setprio(0);
  };

  const int NC = F_ / NKS / 128;            // 16 double-chunk phases

  for (int c = 0; c < NC; ++c) {
    const int cur = (c & 1) * 8192;
    const int nxt = cur ^ 8192;
    const bool pf = (c + 1 < NC);
    const int kc = (c + 1) * 128;           // k-base (in half) of next phase
    __syncthreads();                        // cur staged; nxt's readers done
    int4 kr0, kr1, vr0, vr1;
    if (pf) {                               // T14: sub0' loads under compute
      kr0 = *(const int4*)(ksrc + kg[0]);
      kr1 = *(const int4*)(ksrc + kg[1]);
      vr0 = *(const int4*)(vsrc + vg[0]);
      vr1 = *(const int4*)(vsrc + vg[1]);
    }

    const u16* K0 = sm + cur;               // sub0 K
    const u16* V0 = sm + 16384 + cur;       // sub0 V
    const u16* K1 = K0 + 4096;              // sub1 K
    const u16* V1 = V0 + 4096;              // sub1 V

    // groups: g0=(sub0,kh0) g1=(sub0,kh1) g2=(sub1,kh0) g3=(sub1,kh1)
    f32x16 sA0 = ZERO16, sA1 = ZERO16;
    Sg(K0, sA0, sA1);                       // S(g0)
    f32x16 sB0 = ZERO16, sB1 = ZERO16;
    Sg(K0 + 32 * 64, sB0, sB1);             // S(g1)
    EPg(V0, 0, sA0, sA1);                   // E(g0) || S(g1); PV(g0)

    if (pf) {                               // stage sub0' (V scaled); load sub1'
      *(int4*)(sm + nxt + off_l[0])         = kr0;
      *(int4*)(sm + nxt + off_l[1])         = kr1;
      *(int4*)(sm + 16384 + nxt + off_l[0]) = vscale16(vr0, kc + kw);
      *(int4*)(sm + 16384 + nxt + off_l[1]) = vscale16(vr1, kc + kw);
      kr0 = *(const int4*)(ksrc + 64 * I_ + kg[0]);
      kr1 = *(const int4*)(ksrc + 64 * I_ + kg[1]);
      vr0 = *(const int4*)(vsrc + 64 + vg[0]);
      vr1 = *(const int4*)(vsrc + 64 + vg[1]);
    }

    f32x16 sC0 = ZERO16, sC1 = ZERO16;
    Sg(K1, sC0, sC1);                       // S(g2)
    EPg(V0, 1, sB0, sB1);                   // E(g1) || S(g2); PV(g1)
    f32x16 sD0 = ZERO16, sD1 = ZERO16;
    Sg(K1 + 32 * 64, sD0, sD1);             // S(g3)
    EPg(V1, 0, sC0, sC1);                   // E(g2) || S(g3); PV(g2)

    if (pf) {                               // stage sub1' (V scaled)
      *(int4*)(sm + nxt + 4096 + off_l[0])         = kr0;
      *(int4*)(sm + nxt + 4096 + off_l[1])         = kr1;
      *(int4*)(sm + 16384 + nxt + 4096 + off_l[0]) = vscale16(vr0, kc + 64 + kw);
      *(int4*)(sm + 16384 + nxt + 4096 + off_l[1]) = vscale16(vr1, kc + 64 + kw);
      ksrc += 128 * I_;
      vsrc += 128;
    }
    EPg(V1, 1, sD0, sD1);                   // E(g3); PV(g3)
  }

  if (ks == 0) {
    float* ob = out + ((size_t)b * F_ + q0 + w * 64) * I_;
#pragma unroll
    for (int r = 0; r < 16; ++r) {
      const int qr = (r & 3) + 8 * (r >> 2) + 4 * lh;   // C/D row mapping
      ob[(size_t)qr * I_ + l31]              = o00[r];
      ob[(size_t)qr * I_ + 32 + l31]         = o01[r];
      ob[(size_t)(32 + qr) * I_ + l31]       = o10[r];
      ob[(size_t)(32 + qr) * I_ + 32 + l31]  = o11[r];
    }
  } else {
    u16* pb = pout + ((size_t)b * F_ + q0 + w * 64) * I_;
#pragma unroll
    for (int r = 0; r < 16; ++r) {
      const int qr = (r & 3) + 8 * (r >> 2) + 4 * lh;
      pb[(size_t)qr * I_ + l31]              = f2b(o00[r]);
      pb[(size_t)qr * I_ + 32 + l31]         = f2b(o01[r]);
      pb[(size_t)(32 + qr) * I_ + l31]       = f2b(o10[r]);
      pb[(size_t)(32 + qr) * I_ + 32 + l31]  = f2b(o11[r]);
    }
  }
}

// ---------------------------------------------------------------------------
// Kernel 4: out += bf16 partial (k-split reduction). 8 elems/thread.
// ---------------------------------------------------------------------------
__global__ __launch_bounds__(256) void reduce_k(float* __restrict__ out,
                                                const u16* __restrict__ pout) {
  const size_t i = ((size_t)blockIdx.x * 256 + threadIdx.x) * 8;
  float4 a0 = *(const float4*)(out + i);
  float4 a1 = *(const float4*)(out + i + 4);
  int4 praw = *(const int4*)(pout + i);
  u16 es[8];
  *(int4*)es = praw;
  a0.x += b2f(es[0]); a0.y += b2f(es[1]); a0.z += b2f(es[2]); a0.w += b2f(es[3]);
  a1.x += b2f(es[4]); a1.y += b2f(es[5]); a1.z += b2f(es[6]); a1.w += b2f(es[7]);
  *(float4*)(out + i)     = a0;
  *(float4*)(out + i + 4) = a1;
}

// ---------------------------------------------------------------------------
extern "C" void kernel_launch(void* const* d_in, const int* in_sizes, int n_in,
                              void* d_out, int out_size, void* d_ws,
                              size_t ws_size, hipStream_t stream) {
  const float* x  = (const float*)d_in[0];
  const float* Wq = (const float*)d_in[1];
  const float* Wk = (const float*)d_in[2];
  const float* Wv = (const float*)d_in[3];
  float* out = (float*)d_out;

  // workspace: qn, kn, vt (bf16, B*F*I each); zp (f32 [NQS][B][F]);
  //            pout (bf16 [B][F][I] k-split partial)
  const size_t NBF = (size_t)B_ * F_ * I_;
  u16* qn   = (u16*)d_ws;
  u16* kn   = qn + NBF;
  u16* vt   = kn + NBF;
  float* zp = (float*)(vt + NBF);
  u16* pout = (u16*)(zp + (size_t)NQS * B_ * F_);

  qkv_ln_k<<<dim3(F_ / 64, B_), 256, 0, stream>>>(x, Wq, Wk, Wv, qn, kn, vt);
  // 1024 blocks, XCD-chunked swizzle (16 k-tiles x 16 b x NQS q-quarters)
  attn_stats_k<<<dim3(1024), 256, 0, stream>>>(qn, kn, zp);
  // vscale fused into attn_out at V-stage time (pk2-optimized)
  attn_out_k<<<dim3(512), 256, 0, stream>>>(qn, kn, vt, zp, out, pout);
  reduce_k<<<dim3((int)(NBF / 2048)), 256, 0, stream>>>(out, pout);
}

// Round 16
// 225.047 us; speedup vs baseline: 1.0339x; 1.0339x over previous
//
#include <hip/hip_runtime.h>
#include <math.h>

// Problem constants (fixed-shape problem)
#define B_  16
#define D_  37
#define F_  4096
#define I_  64
#define EPS 1e-5f
// softmax scale 1/sqrt(64) folded with log2(e) into q at projection time,
// so S_mfma = att*log2e and softmax is a raw exp2. |att|<=8 (LN rows have
// norm exactly 8) -> exp2(S) <= 2^11.6: no max pass, bf16-safe unnormalized P.
#define QSCALE 0.18033688011112042f
#define NQS 2           // stats q-split (partial-Z planes)
#define NKS 2           // out k-split (f32 out + bf16 partial)

typedef unsigned short u16;
typedef __bf16 bf16x8 __attribute__((ext_vector_type(8)));
typedef __bf16 bf16x2v __attribute__((ext_vector_type(2)));
typedef float  f32x16 __attribute__((ext_vector_type(16)));
typedef float  f32x2v __attribute__((ext_vector_type(2)));
typedef unsigned int u32x4 __attribute__((ext_vector_type(4)));
typedef int i32x2 __attribute__((ext_vector_type(2)));

#define ZERO16 {0,0,0,0, 0,0,0,0, 0,0,0,0, 0,0,0,0}
#define MFMA32(a, b, c) __builtin_amdgcn_mfma_f32_32x32x16_bf16((a), (b), (c), 0, 0, 0)

#if __has_builtin(__builtin_amdgcn_exp2f)
#define EX2(x) __builtin_amdgcn_exp2f(x)
#else
#define EX2(x) exp2f(x)
#endif
#if __has_builtin(__builtin_amdgcn_rcpf)
#define RCP(x) __builtin_amdgcn_rcpf(x)
#else
#define RCP(x) (1.f / (x))
#endif

// fp32 -> bf16 RNE (scalar)
__device__ __forceinline__ u16 f2b(float f) {
  unsigned u = __builtin_bit_cast(unsigned, f);
  return (u16)((u + 0x7fffu + ((u >> 16) & 1u)) >> 16);
}
// bf16 bits -> fp32
__device__ __forceinline__ float b2f(u16 h) {
  return __builtin_bit_cast(float, (unsigned)h << 16);
}
// pack two fp32 -> bf16x2 (one v_cvt_pk_bf16_f32, RNE -- same rounding as f2b)
__device__ __forceinline__ unsigned pk2(float lo, float hi) {
  f32x2v f = {lo, hi};
  bf16x2v h = __builtin_convertvector(f, bf16x2v);
  return __builtin_bit_cast(unsigned, h);
}

// half-wave register swap (v_permlane32_swap_b32 on gfx950)
__device__ __forceinline__ void plswap(unsigned& a, unsigned& b) {
#if __has_builtin(__builtin_amdgcn_permlane32_swap)
  i32x2 r = __builtin_amdgcn_permlane32_swap((int)a, (int)b, false, false);
  a = (unsigned)r[0];
  b = (unsigned)r[1];
#else
  const int lh = (int)((threadIdx.x & 63) >> 5);
  unsigned pa = (unsigned)__shfl_xor((int)a, 32, 64);
  unsigned pb = (unsigned)__shfl_xor((int)b, 32, 64);
  unsigned na = lh ? pb : a;
  unsigned nb = lh ? b : pa;
  a = na;
  b = nb;
#endif
}

// From one S^T 32x32 C-block (rows=k, cols=q), build two PV A-fragments
// (m=q, contraction k): f0 = k 0..15, f1 = k 16..31 of this block.
// C-reg r holds k=(r&3)+8*(r>>2)+4*lh; A-frag VGPR j needs k=lh*8+2j(+1).
__device__ __forceinline__ void build_af(const f32x16& s, bf16x8& f0, bf16x8& f1) {
  float e[16];
#pragma unroll
  for (int r = 0; r < 16; ++r) e[r] = EX2(s[r]);
  unsigned a = pk2(e[0], e[1]),   bq = pk2(e[2], e[3]);
  unsigned c = pk2(e[4], e[5]),   d  = pk2(e[6], e[7]);
  plswap(a, c);
  plswap(bq, d);
  u32x4 v0 = {a, bq, c, d};
  f0 = __builtin_bit_cast(bf16x8, v0);
  unsigned ee = pk2(e[8], e[9]),  ff = pk2(e[10], e[11]);
  unsigned g  = pk2(e[12], e[13]), h = pk2(e[14], e[15]);
  plswap(ee, g);
  plswap(ff, h);
  u32x4 v1 = {ee, ff, g, h};
  f1 = __builtin_bit_cast(bf16x8, v1);
}

// ---------------------------------------------------------------------------
// Swizzled LDS tiles: logical [rows][64] bf16, elem (r,c) at
//   r*64 + ((c>>3 ^ (r&7))<<3) + (c&7)
// -> 16B-aligned b128 reads AND conflict-free banks without padding.
// ---------------------------------------------------------------------------
__device__ __forceinline__ bf16x8 ldfrag(const u16* base, int row, int kb) {
  return *(const bf16x8*)(base + (row << 6) + ((kb ^ (row & 7)) << 3));
}
// hoisted-staging helpers: LDS offset and global offset for chunk index c
__device__ __forceinline__ int soff_l(int c) {
  const int r = c >> 3, cb = c & 7;
  return (r << 6) + ((cb ^ (r & 7)) << 3);
}
__device__ __forceinline__ int soff_g(int c, int spitch) {
  return (c >> 3) * spitch + ((c & 7) << 3);
}

// XCD-chunked bijective block swizzle for 512-block 1-D grids (8 XCDs x 64):
// clusters blocks that stream the same K/V (or Q) panels onto one XCD's L2.
__device__ __forceinline__ int swz512(int wg) {
  return (wg & 7) * 64 + (wg >> 3);
}

// ---------------------------------------------------------------------------
// Kernel 1: qkv projection + LayerNorm -> bf16 (r10-verified). W columns in
// 120 VGPRs, x staged transposed xs[64][44]; 10 broadcast ds_read_b128 +
// 120 FMA per output row. v written transposed vt[b][i][f] via vtile.
// ---------------------------------------------------------------------------
__global__ __launch_bounds__(256) void qkv_ln_k(
    const float* __restrict__ x,
    const float* __restrict__ Wq, const float* __restrict__ Wk,
    const float* __restrict__ Wv,
    u16* __restrict__ qn, u16* __restrict__ kn, u16* __restrict__ vt) {
  __shared__ __align__(16) float xs[64 * 44];   // [fl][d], pad 44
  __shared__ __align__(16) u16 vtile[64 * 72];

  const int t = threadIdx.x;
  const int b = blockIdx.y;
  const int f0 = blockIdx.x * 64;
  const int lane = t & 63, w = t >> 6;

  // W columns (i = lane) into registers; coalesced, L1/L2-shared.
  float wq[40], wk[40], wv[40];
#pragma unroll
  for (int d = 0; d < D_; ++d) {
    wq[d] = Wq[d * I_ + lane];
    wk[d] = Wk[d * I_ + lane];
    wv[d] = Wv[d * I_ + lane];
  }
#pragma unroll
  for (int d = D_; d < 40; ++d) { wq[d] = 0.f; wk[d] = 0.f; wv[d] = 0.f; }

  // stage x transposed: xs[fl][d] = x[b][d][f0+fl] (global reads coalesced)
  const float* xb = x + (size_t)b * D_ * F_ + f0;
  for (int i = t; i < D_ * 64; i += 256) {
    const int d = i >> 6, fl = i & 63;
    xs[fl * 44 + d] = xb[(size_t)d * F_ + fl];
  }
  // zero the d-pad (37..39) so padded FMA adds exact 0
  if (t < 192) {
    const int fl = t / 3, dp = 37 + (t % 3);
    xs[fl * 44 + dp] = 0.f;
  }
  __syncthreads();

  for (int it = 0; it < 16; ++it) {
    const int fl = w * 16 + it;
    const float* xr = &xs[fl * 44];
    float hq = 0.f, hk = 0.f, hv = 0.f;
#pragma unroll
    for (int j = 0; j < 10; ++j) {
      const float4 xv = *(const float4*)(xr + j * 4);   // broadcast b128
      hq = fmaf(xv.x, wq[4*j+0], hq); hk = fmaf(xv.x, wk[4*j+0], hk); hv = fmaf(xv.x, wv[4*j+0], hv);
      hq = fmaf(xv.y, wq[4*j+1], hq); hk = fmaf(xv.y, wk[4*j+1], hk); hv = fmaf(xv.y, wv[4*j+1], hv);
      hq = fmaf(xv.z, wq[4*j+2], hq); hk = fmaf(xv.z, wk[4*j+2], hk); hv = fmaf(xv.z, wv[4*j+2], hv);
      hq = fmaf(xv.w, wq[4*j+3], hq); hk = fmaf(xv.w, wk[4*j+3], hk); hv = fmaf(xv.w, wv[4*j+3], hv);
    }
    auto lnorm = [&](float a) -> float {
      float s = a;
#pragma unroll
      for (int o = 32; o > 0; o >>= 1) s += __shfl_xor(s, o, 64);
      const float mu = s * (1.f / 64.f);
      const float d0 = a - mu;
      float v = d0 * d0;
#pragma unroll
      for (int o = 32; o > 0; o >>= 1) v += __shfl_xor(v, o, 64);
      return d0 * rsqrtf(v * (1.f / 64.f) + EPS);
    };
    const size_t fo = ((size_t)b * F_ + f0 + fl) * I_ + lane;
    qn[fo] = f2b(lnorm(hq) * QSCALE);
    kn[fo] = f2b(lnorm(hk));
    vtile[lane * 72 + fl] = f2b(lnorm(hv));
  }
  __syncthreads();
  for (int p = 0; p < 2; ++p) {
    const int c = p * 256 + t;
    const int r = c >> 3, off = (c & 7) * 8;
    const int4 v = *(const int4*)&vtile[r * 72 + off];
    *(int4*)(vt + ((size_t)b * I_ + r) * F_ + f0 + off) = v;
  }
}

// ---------------------------------------------------------------------------
// Kernel 2: partial column-softmax sums zp[qh][b][k] = sum_{q in half}
// exp2(S). r9-verified: double-chunk phases, sub-granular T14, direct K
// hoist, intra-wave MFMA/VALU pipeline (M(g); M(g+1); E(g); ...).
// NQS=2 / grid 512 / (256,2): r14 (wide-K) and r15 (NQS=4 + (256,3))
// both measured worse -- this is the verified-best stats configuration.
// ---------------------------------------------------------------------------
__global__ __launch_bounds__(256, 2) void attn_stats_k(
    const u16* __restrict__ qn, const u16* __restrict__ kn,
    float* __restrict__ zp) {
  __shared__ __align__(16) u16 sm[16384];   // 32 KB: Q dbuf 2 x (2 x 4096)

  const int t = threadIdx.x, lane = t & 63, w = t >> 6;
  const int l31 = lane & 31, lh = lane >> 5;
  // XCD-chunked decode: 16 consecutive logical ids share (b,qh).
  const int lg = swz512((int)blockIdx.x);
  const int k0 = (lg & 15) * 256, b = (lg >> 4) & 15, qh = lg >> 8;

  // hoist own 64-k B-fragments directly from global (one-time, 8 loads)
  const u16* kp = kn + ((size_t)b * F_ + k0 + w * 64 + l31) * I_ + lh * 8;
  bf16x8 kf[2][4];
#pragma unroll
  for (int kb2 = 0; kb2 < 2; ++kb2)
#pragma unroll
    for (int ic = 0; ic < 4; ++ic)
      kf[kb2][ic] = *(const bf16x8*)(kp + kb2 * 32 * I_ + ic * 16);

  // hoisted Q staging offsets (2 chunks16B per thread per 64-q sub-tile)
  int qoff_l[2], qoff_g[2];
#pragma unroll
  for (int p = 0; p < 2; ++p) {
    const int c = p * 256 + t;
    qoff_l[p] = soff_l(c);
    qoff_g[p] = soff_g(c, 64);
  }

  const u16* qsrc = qn + ((size_t)b * F_ + qh * (F_ / NQS)) * I_;
  // prologue: stage phase 0 (both subs) into buffer 0
#pragma unroll
  for (int s = 0; s < 2; ++s)
#pragma unroll
    for (int p = 0; p < 2; ++p)
      *(int4*)(sm + s * 4096 + qoff_l[p]) =
          *(const int4*)(qsrc + s * 64 * I_ + qoff_g[p]);
  qsrc += 128 * I_;

  float Zc[2][2] = {{0.f, 0.f}, {0.f, 0.f}};  // [qb][kb]

  // MFMA group (sub given by Qc, qb): 4 ldfrag + 8 MFMA into t0(kb0), t1(kb1)
  auto Mg = [&](const u16* Qc, int qb, f32x16& t0, f32x16& t1) {
    __builtin_amdgcn_s_setprio(1);
#pragma unroll
    for (int ic = 0; ic < 4; ++ic) {
      const bf16x8 qv = ldfrag(Qc + qb * 32 * 64, l31, ic * 2 + lh);
      t0 = MFMA32(qv, kf[0][ic], t0);
      t1 = MFMA32(qv, kf[1][ic], t1);
    }
    __builtin_amdgcn_s_setprio(0);
  };
  // exp2-accumulate group (VALU)
  auto Eg = [&](int qb, const f32x16& t0, const f32x16& t1) {
#pragma unroll
    for (int r = 0; r < 16; ++r) {
      Zc[qb][0] += EX2(t0[r]);
      Zc[qb][1] += EX2(t1[r]);
    }
  };

  const int NC = F_ / NQS / 128;            // 16 double-chunk phases

  for (int c = 0; c < NC; ++c) {
    const int cur = (c & 1) * 8192;
    const int nxt = cur ^ 8192;
    const bool pf = (c + 1 < NC);
    __syncthreads();                        // cur staged; nxt's readers done
    int4 qr0, qr1;
    if (pf) {                               // T14: sub0' loads under compute
      qr0 = *(const int4*)(qsrc + qoff_g[0]);
      qr1 = *(const int4*)(qsrc + qoff_g[1]);
    }

    // pipeline: M(g) ; M(g+1) ; E(g) ...  (E overlaps next group's MFMAs)
    f32x16 sA0 = ZERO16, sA1 = ZERO16;
    Mg(sm + cur, 0, sA0, sA1);              // g0 = (sub0, qb0)
    f32x16 sB0 = ZERO16, sB1 = ZERO16;
    Mg(sm + cur, 1, sB0, sB1);              // g1 = (sub0, qb1)
    Eg(0, sA0, sA1);                        // E(g0) || M(g1)

    if (pf) {                               // stage sub0' ; load sub1'
      *(int4*)(sm + nxt + qoff_l[0]) = qr0;
      *(int4*)(sm + nxt + qoff_l[1]) = qr1;
      qr0 = *(const int4*)(qsrc + 64 * I_ + qoff_g[0]);
      qr1 = *(const int4*)(qsrc + 64 * I_ + qoff_g[1]);
    }

    f32x16 sC0 = ZERO16, sC1 = ZERO16;
    Mg(sm + cur + 4096, 0, sC0, sC1);       // g2 = (sub1, qb0)
    Eg(1, sB0, sB1);                        // E(g1) || M(g2)
    f32x16 sD0 = ZERO16, sD1 = ZERO16;
    Mg(sm + cur + 4096, 1, sD0, sD1);       // g3 = (sub1, qb1)
    Eg(0, sC0, sC1);                        // E(g2) || M(g3)

    if (pf) {                               // stage sub1'
      *(int4*)(sm + nxt + 4096 + qoff_l[0]) = qr0;
      *(int4*)(sm + nxt + 4096 + qoff_l[1]) = qr1;
      qsrc += 128 * I_;
    }
    Eg(1, sD0, sD1);                        // E(g3)
  }

#pragma unroll
  for (int kb2 = 0; kb2 < 2; ++kb2) {
    float Zt = Zc[0][kb2] + Zc[1][kb2];
    Zt += __shfl_xor(Zt, 32, 64);
    if (lane < 32)
      zp[((size_t)qh * B_ + b) * F_ + k0 + w * 64 + kb2 * 32 + lane] = Zt;
  }
}

// ---------------------------------------------------------------------------
// Kernel 3: partial out over a k-half. r13-verified (best attn_out: 75.9us):
// 256-q tile, 64-q waves, double-chunk phases, sub-granular T14, direct Q
// hoist, intra-wave MFMA/VALU pipeline, fused V-scaling at stage-write time
// with pk2 (v_cvt_pk_bf16_f32). rz table sums NQS=2 zp planes.
// ks=0 -> f32 out; ks=1 -> bf16 partial (reduce_k folds).
// ---------------------------------------------------------------------------
__global__ __launch_bounds__(256, 2) void attn_out_k(
    const u16* __restrict__ qn, const u16* __restrict__ kn,
    const u16* __restrict__ vt, const float* __restrict__ zp,
    float* __restrict__ out, u16* __restrict__ pout) {
  __shared__ __align__(16) u16 sm[32768];   // 64 KB: K dbuf 2x8192, V at 16384+
  __shared__ __align__(16) float rzs[F_ / NKS];  // 8 KB: 1/Z for this k-half

  const int t = threadIdx.x, lane = t & 63, w = t >> 6;
  const int l31 = lane & 31, lh = lane >> 5;
  // XCD-chunked decode: 16 consecutive logical ids share (b,ks).
  const int lg = swz512((int)blockIdx.x);
  const int q0 = (lg & 15) * 256, b = (lg >> 4) & 15, ks = lg >> 8;

  // ---- rz table: rzs[k] = RCP(sum_qh zp[qh][b][k]) for this k-half ----
  {
    const float* zb = zp + (size_t)b * F_ + ks * (F_ / NKS);
    const size_t PL = (size_t)B_ * F_;
    const int k8 = t * 8;                   // 256 thr x 8 = 2048
    float4 s0 = *(const float4*)(zb + k8);
    float4 s1 = *(const float4*)(zb + k8 + 4);
#pragma unroll
    for (int qh = 1; qh < NQS; ++qh) {
      const float4 a0 = *(const float4*)(zb + qh * PL + k8);
      const float4 a1 = *(const float4*)(zb + qh * PL + k8 + 4);
      s0.x += a0.x; s0.y += a0.y; s0.z += a0.z; s0.w += a0.w;
      s1.x += a1.x; s1.y += a1.y; s1.z += a1.z; s1.w += a1.w;
    }
    float4 r0, r1;
    r0.x = RCP(s0.x); r0.y = RCP(s0.y); r0.z = RCP(s0.z); r0.w = RCP(s0.w);
    r1.x = RCP(s1.x); r1.y = RCP(s1.y); r1.z = RCP(s1.z); r1.w = RCP(s1.w);
    *(float4*)(rzs + k8)     = r0;
    *(float4*)(rzs + k8 + 4) = r1;
  }
  __syncthreads();                          // rzs visible to all

  // hoist own 64-q B-fragments directly from global (one-time, 8 loads)
  const u16* qp = qn + ((size_t)b * F_ + q0 + w * 64 + l31) * I_ + lh * 8;
  bf16x8 qf[2][4];
#pragma unroll
  for (int qb2 = 0; qb2 < 2; ++qb2)
#pragma unroll
    for (int ic = 0; ic < 4; ++ic)
      qf[qb2][ic] = *(const bf16x8*)(qp + qb2 * 32 * I_ + ic * 16);

  // hoisted staging offsets (2 K + 2 V chunks16B per thread per 64-k sub)
  int off_l[2], kg[2], vg[2];
#pragma unroll
  for (int p = 0; p < 2; ++p) {
    const int c = p * 256 + t;
    off_l[p] = soff_l(c);
    kg[p] = soff_g(c, 64);
    vg[p] = soff_g(c, F_);
  }
  const int kw = (t & 7) * 8;               // k-col base of this thread's 16B

  // scale a staged V 16B-chunk by rzs[kb..kb+7]; pk2 = v_cvt_pk_bf16_f32
  auto vscale16 = [&](int4 raw, int kb) -> int4 {
    u16 es[8];
    *(int4*)es = raw;
    const float4 r0 = *(const float4*)(rzs + kb);
    const float4 r1 = *(const float4*)(rzs + kb + 4);
    unsigned o01 = pk2(b2f(es[0]) * r0.x, b2f(es[1]) * r0.y);
    unsigned o23 = pk2(b2f(es[2]) * r0.z, b2f(es[3]) * r0.w);
    unsigned o45 = pk2(b2f(es[4]) * r1.x, b2f(es[5]) * r1.y);
    unsigned o67 = pk2(b2f(es[6]) * r1.z, b2f(es[7]) * r1.w);
    u32x4 o = {o01, o23, o45, o67};
    return __builtin_bit_cast(int4, o);
  };

  const u16* ksrc = kn + ((size_t)b * F_ + ks * (F_ / NKS)) * I_;
  const u16* vsrc = vt + (size_t)b * I_ * F_ + ks * (F_ / NKS);
  // prologue: stage phase 0 (both subs) into buffers 0 (V scaled)
#pragma unroll
  for (int s = 0; s < 2; ++s)
#pragma unroll
    for (int p = 0; p < 2; ++p) {
      *(int4*)(sm + s * 4096 + off_l[p]) =
          *(const int4*)(ksrc + s * 64 * I_ + kg[p]);
      *(int4*)(sm + 16384 + s * 4096 + off_l[p]) =
          vscale16(*(const int4*)(vsrc + s * 64 + vg[p]), s * 64 + kw);
    }
  ksrc += 128 * I_;
  vsrc += 128;

  f32x16 o00 = ZERO16, o01 = ZERO16, o10 = ZERO16, o11 = ZERO16; // [qb][ih]

  // S group: one kh-half of one sub (Kc pre-offset): 4 ldfrag + 8 MFMA
  auto Sg = [&](const u16* Kc, f32x16& t0, f32x16& t1) {
    __builtin_amdgcn_s_setprio(1);
#pragma unroll
    for (int ic = 0; ic < 4; ++ic) {
      const bf16x8 ak = ldfrag(Kc, l31, ic * 2 + lh);
      t0 = MFMA32(ak, qf[0][ic], t0);
      t1 = MFMA32(ak, qf[1][ic], t1);
    }
    __builtin_amdgcn_s_setprio(0);
  };
  // exp2+transpose (VALU) then PV for that kh-half (kb4 = 2kh, 2kh+1)
  auto EPg = [&](const u16* Vc, int kh, const f32x16& t0, const f32x16& t1) {
    bf16x8 a0, a1, b0, b1;
    build_af(t0, a0, a1);                   // qb0: kb4=2kh -> a0, 2kh+1 -> a1
    build_af(t1, b0, b1);                   // qb1
    __builtin_amdgcn_s_setprio(1);
    {
      const int kb4 = kh * 2;
      const bf16x8 bv0 = ldfrag(Vc, l31, kb4 * 2 + lh);
      const bf16x8 bv1 = ldfrag(Vc + 32 * 64, l31, kb4 * 2 + lh);
      o00 = MFMA32(a0, bv0, o00);
      o01 = MFMA32(a0, bv1, o01);
      o10 = MFMA32(b0, bv0, o10);
      o11 = MFMA32(b0, bv1, o11);
    }
    {
      const int kb4 = kh * 2 + 1;
      const bf16x8 bv0 = ldfrag(Vc, l31, kb4 * 2 + lh);
      const bf16x8 bv1 = ldfrag(Vc + 32 * 64, l31, kb4 * 2 + lh);
      o00 = MFMA32(a1, bv0, o00);
      o01 = MFMA32(a1, bv1, o01);
      o10 = MFMA32(b1, bv0, o10);
      o11 = MFMA32(b1, bv1, o11);
    }
    __builtin_amdgcn_s_setprio(0);
  };

  const int NC = F_ / NKS / 128;            // 16 double-chunk phases

  for (int c = 0; c < NC; ++c) {
    const int cur = (c & 1) * 8192;
    const int nxt = cur ^ 8192;
    const bool pf = (c + 1 < NC);
    const int kc = (c + 1) * 128;           // k-base (in half) of next phase
    __syncthreads();                        // cur staged; nxt's readers done
    int4 kr0, kr1, vr0, vr1;
    if (pf) {                               // T14: sub0' loads under compute
      kr0 = *(const int4*)(ksrc + kg[0]);
      kr1 = *(const int4*)(ksrc + kg[1]);
      vr0 = *(const int4*)(vsrc + vg[0]);
      vr1 = *(const int4*)(vsrc + vg[1]);
    }

    const u16* K0 = sm + cur;               // sub0 K
    const u16* V0 = sm + 16384 + cur;       // sub0 V
    const u16* K1 = K0 + 4096;              // sub1 K
    const u16* V1 = V0 + 4096;              // sub1 V

    // groups: g0=(sub0,kh0) g1=(sub0,kh1) g2=(sub1,kh0) g3=(sub1,kh1)
    f32x16 sA0 = ZERO16, sA1 = ZERO16;
    Sg(K0, sA0, sA1);                       // S(g0)
    f32x16 sB0 = ZERO16, sB1 = ZERO16;
    Sg(K0 + 32 * 64, sB0, sB1);             // S(g1)
    EPg(V0, 0, sA0, sA1);                   // E(g0) || S(g1); PV(g0)

    if (pf) {                               // stage sub0' (V scaled); load sub1'
      *(int4*)(sm + nxt + off_l[0])         = kr0;
      *(int4*)(sm + nxt + off_l[1])         = kr1;
      *(int4*)(sm + 16384 + nxt + off_l[0]) = vscale16(vr0, kc + kw);
      *(int4*)(sm + 16384 + nxt + off_l[1]) = vscale16(vr1, kc + kw);
      kr0 = *(const int4*)(ksrc + 64 * I_ + kg[0]);
      kr1 = *(const int4*)(ksrc + 64 * I_ + kg[1]);
      vr0 = *(const int4*)(vsrc + 64 + vg[0]);
      vr1 = *(const int4*)(vsrc + 64 + vg[1]);
    }

    f32x16 sC0 = ZERO16, sC1 = ZERO16;
    Sg(K1, sC0, sC1);                       // S(g2)
    EPg(V0, 1, sB0, sB1);                   // E(g1) || S(g2); PV(g1)
    f32x16 sD0 = ZERO16, sD1 = ZERO16;
    Sg(K1 + 32 * 64, sD0, sD1);             // S(g3)
    EPg(V1, 0, sC0, sC1);                   // E(g2) || S(g3); PV(g2)

    if (pf) {                               // stage sub1' (V scaled)
      *(int4*)(sm + nxt + 4096 + off_l[0])         = kr0;
      *(int4*)(sm + nxt + 4096 + off_l[1])         = kr1;
      *(int4*)(sm + 16384 + nxt + 4096 + off_l[0]) = vscale16(vr0, kc + 64 + kw);
      *(int4*)(sm + 16384 + nxt + 4096 + off_l[1]) = vscale16(vr1, kc + 64 + kw);
      ksrc += 128 * I_;
      vsrc += 128;
    }
    EPg(V1, 1, sD0, sD1);                   // E(g3); PV(g3)
  }

  if (ks == 0) {
    float* ob = out + ((size_t)b * F_ + q0 + w * 64) * I_;
#pragma unroll
    for (int r = 0; r < 16; ++r) {
      const int qr = (r & 3) + 8 * (r >> 2) + 4 * lh;   // C/D row mapping
      ob[(size_t)qr * I_ + l31]              = o00[r];
      ob[(size_t)qr * I_ + 32 + l31]         = o01[r];
      ob[(size_t)(32 + qr) * I_ + l31]       = o10[r];
      ob[(size_t)(32 + qr) * I_ + 32 + l31]  = o11[r];
    }
  } else {
    u16* pb = pout + ((size_t)b * F_ + q0 + w * 64) * I_;
#pragma unroll
    for (int r = 0; r < 16; ++r) {
      const int qr = (r & 3) + 8 * (r >> 2) + 4 * lh;
      pb[(size_t)qr * I_ + l31]              = f2b(o00[r]);
      pb[(size_t)qr * I_ + 32 + l31]         = f2b(o01[r]);
      pb[(size_t)(32 + qr) * I_ + l31]       = f2b(o10[r]);
      pb[(size_t)(32 + qr) * I_ + 32 + l31]  = f2b(o11[r]);
    }
  }
}

// ---------------------------------------------------------------------------
// Kernel 4: out += bf16 partial (k-split reduction). 8 elems/thread.
// ---------------------------------------------------------------------------
__global__ __launch_bounds__(256) void reduce_k(float* __restrict__ out,
                                                const u16* __restrict__ pout) {
  const size_t i = ((size_t)blockIdx.x * 256 + threadIdx.x) * 8;
  float4 a0 = *(const float4*)(out + i);
  float4 a1 = *(const float4*)(out + i + 4);
  int4 praw = *(const int4*)(pout + i);
  u16 es[8];
  *(int4*)es = praw;
  a0.x += b2f(es[0]); a0.y += b2f(es[1]); a0.z += b2f(es[2]); a0.w += b2f(es[3]);
  a1.x += b2f(es[4]); a1.y += b2f(es[5]); a1.z += b2f(es[6]); a1.w += b2f(es[7]);
  *(float4*)(out + i)     = a0;
  *(float4*)(out + i + 4) = a1;
}

// ---------------------------------------------------------------------------
extern "C" void kernel_launch(void* const* d_in, const int* in_sizes, int n_in,
                              void* d_out, int out_size, void* d_ws,
                              size_t ws_size, hipStream_t stream) {
  const float* x  = (const float*)d_in[0];
  const float* Wq = (const float*)d_in[1];
  const float* Wk = (const float*)d_in[2];
  const float* Wv = (const float*)d_in[3];
  float* out = (float*)d_out;

  // workspace: qn, kn, vt (bf16, B*F*I each); zp (f32 [NQS][B][F]);
  //            pout (bf16 [B][F][I] k-split partial)
  const size_t NBF = (size_t)B_ * F_ * I_;
  u16* qn   = (u16*)d_ws;
  u16* kn   = qn + NBF;
  u16* vt   = kn + NBF;
  float* zp = (float*)(vt + NBF);
  u16* pout = (u16*)(zp + (size_t)NQS * B_ * F_);

  qkv_ln_k<<<dim3(F_ / 64, B_), 256, 0, stream>>>(x, Wq, Wk, Wv, qn, kn, vt);
  // 512 blocks, XCD-chunked swizzle (16 k-tiles x 16 b x NQS q-halves)
  attn_stats_k<<<dim3(512), 256, 0, stream>>>(qn, kn, zp);
  // vscale fused into attn_out at V-stage time (pk2-optimized)
  attn_out_k<<<dim3(512), 256, 0, stream>>>(qn, kn, vt, zp, out, pout);
  reduce_k<<<dim3((int)(NBF / 2048)), 256, 0, stream>>>(out, pout);
}